// Round 2
// baseline (96.099 us; speedup 1.0000x reference)
//
#include <hip/hip_runtime.h>

// Problem constants (LX=8, LY=4, D=4, PHYS=2)
#define ETA 0.001f
#define NVEC 16384          // 2 * LX * D^5
#define NB   8192           // LX * D^5

// ---------------------------------------------------------------------------
// Kernel A: delta[b][n] = ETA * ( relu(cfg_b . W1 + b1) . W2[:,n] + b2[n] )
// Grid (16,16): blockIdx.x = n-tile of 1024 (256 thr x float4),
//               blockIdx.y = tile of 8 configs.
// ---------------------------------------------------------------------------
__global__ __launch_bounds__(256) void nn_delta_kernel(
    const int* __restrict__ cfg, const float* __restrict__ W1,
    const float* __restrict__ b1, const float* __restrict__ W2,
    const float* __restrict__ b2, float* __restrict__ delta)
{
    __shared__ float Hs[8][64];
    const int t  = threadIdx.x;
    const int b0 = blockIdx.y * 8;
    const int n4 = blockIdx.x * 256 + t;      // float4 column index (NVEC/4 = 4096)

    // H tile: 8 configs x 64 hidden (512 entries, 2 per thread)
    for (int e = t; e < 8 * 64; e += 256) {
        const int bb = e >> 6, k = e & 63;
        float acc = b1[k];
        const int* c = cfg + (b0 + bb) * 32;
        #pragma unroll
        for (int m = 0; m < 32; ++m)
            acc = fmaf((float)c[m], W1[m * 64 + k], acc);
        Hs[bb][k] = fmaxf(acc, 0.0f);
    }
    __syncthreads();

    float4 acc[8];
    #pragma unroll
    for (int bb = 0; bb < 8; ++bb) acc[bb] = make_float4(0.f, 0.f, 0.f, 0.f);

    const float4* W24 = (const float4*)W2;
    #pragma unroll 4
    for (int k = 0; k < 64; ++k) {
        const float4 w = W24[k * 4096 + n4];          // coalesced b128
        #pragma unroll
        for (int bb = 0; bb < 8; ++bb) {
            const float h = Hs[bb][k];                // LDS broadcast
            acc[bb].x = fmaf(h, w.x, acc[bb].x);
            acc[bb].y = fmaf(h, w.y, acc[bb].y);
            acc[bb].z = fmaf(h, w.z, acc[bb].z);
            acc[bb].w = fmaf(h, w.w, acc[bb].w);
        }
    }
    const float4 bias = ((const float4*)b2)[n4];
    float4* d4 = (float4*)delta;
    #pragma unroll
    for (int bb = 0; bb < 8; ++bb) {
        float4 r;
        r.x = ETA * (acc[bb].x + bias.x);
        r.y = ETA * (acc[bb].y + bias.y);
        r.z = ETA * (acc[bb].z + bias.z);
        r.w = ETA * (acc[bb].w + bias.w);
        d4[(b0 + bb) * 4096 + n4] = r;
    }
}

// ---------------------------------------------------------------------------
// Kernel B: one block per config.
//   1) gather s[x,y,·] = A[·, cfg[x,y]]                     (LDS, 32 KB)
//   2) vec = [bot | top] + delta (delta prefetched to regs)  (LDS, 64 KB)
//   3) factored scan with transposed V:  VT[I*16+i] = V[i][I]
//        phase A: T[I*16+j].u = sum_i VT[I*16+i] * bot2[x,i,j,u]
//        phase B: VT[J*16+j]  = sum_{I,u} T[I*16+j].u * top2[x,I,J,u]
// ---------------------------------------------------------------------------
__global__ __launch_bounds__(256) void contract_kernel(
    const int* __restrict__ cfg, const float* __restrict__ A,
    const float* __restrict__ delta, float* __restrict__ out)
{
    __shared__ float  s[8192];       // 32 KB
    __shared__ float  vec[NVEC];     // 64 KB
    __shared__ float4 T[256];        // 4 KB
    __shared__ float  VT[256];       // 1 KB  (transposed scan vector)

    const int t = threadIdx.x;
    const int b = blockIdx.x;

    // ---- prefetch delta row into registers (global latency hidden by gather)
    float4 dreg[16];
    const float4* dlt = (const float4*)(delta + b * NVEC);
    #pragma unroll
    for (int q = 0; q < 16; ++q) dreg[q] = dlt[q * 256 + t];

    // ---- 1) gather s  (cfg index idx>>8 is block-uniform per iteration)
    const int* cb = cfg + b * 32;
    for (int idx = t; idx < 8192; idx += 256)
        s[idx] = A[idx * 2 + cb[idx >> 8]];
    __syncthreads();

    // ---- 2) build vec (4096 float4 outputs, 16 per thread)
    #pragma unroll
    for (int q = 0; q < 16; ++q) {
        const int m = q * 256 + t;           // float4 index in vec
        const int x = (m >> 8) & 7;
        const int i = (m >> 4) & 15;
        const int j = m & 15;
        const int l = i >> 2, L = i & 3, r = j >> 2, R = j & 3;

        float4 acc = make_float4(0.f, 0.f, 0.f, 0.f);
        if (q < 8) {                          // bot: y=0 (c=0 plane) x y=1
            const float* sA = s + (x * 4 + 0) * 256;
            const float* sB = sA + 256;
            const float4 a4 = *(const float4*)(sA + l * 64 + r * 16);
            #pragma unroll
            for (int u = 0; u < 4; ++u) {
                const float  a  = (u == 0) ? a4.x : (u == 1) ? a4.y : (u == 2) ? a4.z : a4.w;
                const float4 bv = *(const float4*)(sB + L * 64 + R * 16 + u * 4);
                acc.x = fmaf(a, bv.x, acc.x);
                acc.y = fmaf(a, bv.y, acc.y);
                acc.z = fmaf(a, bv.z, acc.z);
                acc.w = fmaf(a, bv.w, acc.w);
            }
        } else {                              // top: y=2 x y=3 (d=0 plane)
            const float* sA = s + (x * 4 + 2) * 256;
            const float* sB = sA + 256;
            const int baseB = L * 64 + R * 16;
            const float4 bvs = make_float4(sB[baseB], sB[baseB + 4], sB[baseB + 8], sB[baseB + 12]);
            const int baseA = l * 64 + r * 16;
            const float4 r0 = *(const float4*)(sA + baseA);
            const float4 r1 = *(const float4*)(sA + baseA + 4);
            const float4 r2 = *(const float4*)(sA + baseA + 8);
            const float4 r3 = *(const float4*)(sA + baseA + 12);
            acc.x = fmaf(r0.x, bvs.x, fmaf(r0.y, bvs.y, fmaf(r0.z, bvs.z, r0.w * bvs.w)));
            acc.y = fmaf(r1.x, bvs.x, fmaf(r1.y, bvs.y, fmaf(r1.z, bvs.z, r1.w * bvs.w)));
            acc.z = fmaf(r2.x, bvs.x, fmaf(r2.y, bvs.y, fmaf(r2.z, bvs.z, r2.w * bvs.w)));
            acc.w = fmaf(r3.x, bvs.x, fmaf(r3.y, bvs.y, fmaf(r3.z, bvs.z, r3.w * bvs.w)));
        }
        const float4 d4 = dreg[q];
        acc.x += d4.x; acc.y += d4.y; acc.z += d4.z; acc.w += d4.w;
        ((float4*)vec)[m] = acc;
    }

    // note: build order differs per-u for q<8 vs round-1 only in load shape,
    // arithmetic order identical.

    VT[t] = 0.0f;                 // init transposed V; racing with build is fine
    __syncthreads();
    if (t == 0) VT[0] = 1.0f;     // V[0][0] = 1
    __syncthreads();

    const float4* bot4 = (const float4*)vec;        // [x*256 + i*16 + j]
    const float4* top4 = (const float4*)(vec + NB); // [x*256 + I*16 + J]

    for (int x = 0; x < 8; ++x) {
        // ---- phase A: thread (I = t>>4, j = t&15)
        {
            const int I = t >> 4, j = t & 15;
            float vv[16];
            *(float4*)&vv[0]  = *(const float4*)(VT + I * 16 + 0);
            *(float4*)&vv[4]  = *(const float4*)(VT + I * 16 + 4);
            *(float4*)&vv[8]  = *(const float4*)(VT + I * 16 + 8);
            *(float4*)&vv[12] = *(const float4*)(VT + I * 16 + 12);
            float4 acc = make_float4(0.f, 0.f, 0.f, 0.f);
            #pragma unroll
            for (int i = 0; i < 16; ++i) {
                const float  vi = vv[i];
                const float4 bv = bot4[x * 256 + i * 16 + j];
                acc.x = fmaf(vi, bv.x, acc.x);
                acc.y = fmaf(vi, bv.y, acc.y);
                acc.z = fmaf(vi, bv.z, acc.z);
                acc.w = fmaf(vi, bv.w, acc.w);
            }
            T[t] = acc;
        }
        __syncthreads();
        // ---- phase B: thread (j = t>>4, J = t&15); in-place VT update is safe
        {
            const int j = t >> 4, J = t & 15;
            float acc = 0.f;
            #pragma unroll
            for (int I = 0; I < 16; ++I) {
                const float4 tv = T[I * 16 + j];
                const float4 pv = top4[x * 256 + I * 16 + J];
                acc = fmaf(tv.x, pv.x, acc);
                acc = fmaf(tv.y, pv.y, acc);
                acc = fmaf(tv.z, pv.z, acc);
                acc = fmaf(tv.w, pv.w, acc);
            }
            VT[J * 16 + j] = acc;
        }
        __syncthreads();
    }

    if (t == 0) out[b] = VT[0];
}

// ---------------------------------------------------------------------------
extern "C" void kernel_launch(void* const* d_in, const int* in_sizes, int n_in,
                              void* d_out, int out_size, void* d_ws, size_t ws_size,
                              hipStream_t stream) {
    const int*   cfg = (const int*)  d_in[0];
    const float* A   = (const float*)d_in[1];
    const float* W1  = (const float*)d_in[2];
    const float* b1  = (const float*)d_in[3];
    const float* W2  = (const float*)d_in[4];
    const float* b2  = (const float*)d_in[5];
    float* out   = (float*)d_out;
    float* delta = (float*)d_ws;                  // ncfg * 16384 floats (8 MB)

    const int ncfg = in_sizes[0] / 32;            // 128

    dim3 gA(16, ncfg / 8);                        // (16, 16)
    nn_delta_kernel<<<gA, 256, 0, stream>>>(cfg, W1, b1, W2, b2, delta);
    contract_kernel<<<ncfg, 256, 0, stream>>>(cfg, A, delta, out);
}

// Round 4
// 90.382 us; speedup vs baseline: 1.0633x; 1.0633x over previous
//
#include <hip/hip_runtime.h>

// Problem constants (LX=8, LY=4, D=4, PHYS=2)
#define ETA 0.001f
#define NVEC 16384          // 2 * LX * D^5
#define NB   8192           // LX * D^5

// ---------------------------------------------------------------------------
// Kernel A: delta[b][n] = ETA * ( relu(cfg_b . W1 + b1) . W2[:,n] + b2[n] )
// Grid (16,16): blockIdx.x = n-tile of 1024 (256 thr x float4),
//               blockIdx.y = tile of 8 configs.
// ---------------------------------------------------------------------------
__global__ __launch_bounds__(256) void nn_delta_kernel(
    const int* __restrict__ cfg, const float* __restrict__ W1,
    const float* __restrict__ b1, const float* __restrict__ W2,
    const float* __restrict__ b2, float* __restrict__ delta)
{
    __shared__ float Hs[8][64];
    const int t  = threadIdx.x;
    const int b0 = blockIdx.y * 8;
    const int n4 = blockIdx.x * 256 + t;      // float4 column index (NVEC/4 = 4096)

    for (int e = t; e < 8 * 64; e += 256) {
        const int bb = e >> 6, k = e & 63;
        float acc = b1[k];
        const int* c = cfg + (b0 + bb) * 32;
        #pragma unroll
        for (int m = 0; m < 32; ++m)
            acc = fmaf((float)c[m], W1[m * 64 + k], acc);
        Hs[bb][k] = fmaxf(acc, 0.0f);
    }
    __syncthreads();

    float4 acc[8];
    #pragma unroll
    for (int bb = 0; bb < 8; ++bb) acc[bb] = make_float4(0.f, 0.f, 0.f, 0.f);

    const float4* W24 = (const float4*)W2;
    #pragma unroll 4
    for (int k = 0; k < 64; ++k) {
        const float4 w = W24[k * 4096 + n4];          // coalesced b128
        #pragma unroll
        for (int bb = 0; bb < 8; ++bb) {
            const float h = Hs[bb][k];                // LDS broadcast
            acc[bb].x = fmaf(h, w.x, acc[bb].x);
            acc[bb].y = fmaf(h, w.y, acc[bb].y);
            acc[bb].z = fmaf(h, w.z, acc[bb].z);
            acc[bb].w = fmaf(h, w.w, acc[bb].w);
        }
    }
    const float4 bias = ((const float4*)b2)[n4];
    float4* d4 = (float4*)delta;
    #pragma unroll
    for (int bb = 0; bb < 8; ++bb) {
        float4 r;
        r.x = ETA * (acc[bb].x + bias.x);
        r.y = ETA * (acc[bb].y + bias.y);
        r.z = ETA * (acc[bb].z + bias.z);
        r.w = ETA * (acc[bb].w + bias.w);
        d4[(b0 + bb) * 4096 + n4] = r;
    }
}

// ---------------------------------------------------------------------------
// Kernel B: one block (512 thr) per config.
//   1) pair-gather s[x,y,.] = A[., cfg[x,y]]               (LDS, 32 KB)
//   2) build bot/top tiles, padded stride-17 rows           (LDS, 2x34.8 KB)
//   3) split scan: waves 0-3: vL = v0^T M0..M3  (T via LDS)
//                  waves 4-7: w  = M7..M4 applied to e0
//      out = vL . w   (4 steps, 8 barriers instead of 16)
// ---------------------------------------------------------------------------
__global__ __launch_bounds__(512) void contract_kernel(
    const int* __restrict__ cfg, const float* __restrict__ A,
    const float* __restrict__ delta, float* __restrict__ out)
{
    __shared__ float  s[8192];          // 32 KB
    __shared__ float4 bot4[8 * 272];    // [x*272 + i*17 + j], 34.8 KB
    __shared__ float4 top4[8 * 272];    // [x*272 + I*17 + J], 34.8 KB
    __shared__ float4 T4[256];          // left:  T[I*16 + j]
    __shared__ float4 U4[16 * 17];      // right: U[I*17 + j]
    __shared__ float  VT[256];          // left state:  VT[I*16+i] = v[i*16+I]
    __shared__ float  Wv[16 * 20];      // right state: Wv[j*20+J] = w[j*16+J]
    __shared__ float  red[8];

    const int t = threadIdx.x;
    const int b = blockIdx.x;

    // ---- 1) gather: each thread handles 2 consecutive s-elements via one b128
    const int* cb = cfg + b * 32;
    const float4* A4 = (const float4*)A;
    #pragma unroll
    for (int k = 0; k < 8; ++k) {
        const int p = k * 512 + t;          // pair index 0..4095
        const float4 w = A4[p];             // {e0.phys0, e0.phys1, e1.phys0, e1.phys1}
        const int c = cb[p >> 7];           // wave-uniform
        float2 r;
        r.x = c ? w.y : w.x;
        r.y = c ? w.w : w.z;
        *(float2*)(s + 2 * p) = r;
    }
    __syncthreads();

    // ---- 2) build bot/top (8 float4 outputs per thread, delta loaded inline)
    const float4* dlt = (const float4*)(delta + b * NVEC);
    #pragma unroll
    for (int q = 0; q < 8; ++q) {
        const int m = q * 512 + t;          // logical vec float4 index 0..4095
        const int x = (m >> 8) & 7;
        const int i = (m >> 4) & 15;
        const int j = m & 15;
        const int l = i >> 2, L = i & 3, r = j >> 2, R = j & 3;

        float4 acc = make_float4(0.f, 0.f, 0.f, 0.f);
        if (q < 4) {                         // bot: y=0 (c=0 plane) x y=1
            const float* sA = s + (x * 4 + 0) * 256;
            const float* sB = sA + 256;
            const float4 a4 = *(const float4*)(sA + l * 64 + r * 16);
            const float4 b0 = *(const float4*)(sB + L * 64 + R * 16 + 0);
            const float4 b1 = *(const float4*)(sB + L * 64 + R * 16 + 4);
            const float4 b2 = *(const float4*)(sB + L * 64 + R * 16 + 8);
            const float4 b3 = *(const float4*)(sB + L * 64 + R * 16 + 12);
            acc.x = fmaf(a4.x, b0.x, fmaf(a4.y, b1.x, fmaf(a4.z, b2.x, a4.w * b3.x)));
            acc.y = fmaf(a4.x, b0.y, fmaf(a4.y, b1.y, fmaf(a4.z, b2.y, a4.w * b3.y)));
            acc.z = fmaf(a4.x, b0.z, fmaf(a4.y, b1.z, fmaf(a4.z, b2.z, a4.w * b3.z)));
            acc.w = fmaf(a4.x, b0.w, fmaf(a4.y, b1.w, fmaf(a4.z, b2.w, a4.w * b3.w)));
        } else {                             // top: y=2 x y=3 (d=0 plane)
            const float* sA = s + (x * 4 + 2) * 256;
            const float* sB = sA + 256;
            const int baseB = L * 64 + R * 16;
            const float4 bvs = make_float4(sB[baseB], sB[baseB + 4], sB[baseB + 8], sB[baseB + 12]);
            const int baseA = l * 64 + r * 16;
            const float4 r0 = *(const float4*)(sA + baseA);
            const float4 r1 = *(const float4*)(sA + baseA + 4);
            const float4 r2 = *(const float4*)(sA + baseA + 8);
            const float4 r3 = *(const float4*)(sA + baseA + 12);
            acc.x = fmaf(r0.x, bvs.x, fmaf(r0.y, bvs.y, fmaf(r0.z, bvs.z, r0.w * bvs.w)));
            acc.y = fmaf(r1.x, bvs.x, fmaf(r1.y, bvs.y, fmaf(r1.z, bvs.z, r1.w * bvs.w)));
            acc.z = fmaf(r2.x, bvs.x, fmaf(r2.y, bvs.y, fmaf(r2.z, bvs.z, r2.w * bvs.w)));
            acc.w = fmaf(r3.x, bvs.x, fmaf(r3.y, bvs.y, fmaf(r3.z, bvs.z, r3.w * bvs.w)));
        }
        const float4 d4 = dlt[m];
        acc.x += d4.x; acc.y += d4.y; acc.z += d4.z; acc.w += d4.w;
        float4* dst = (q < 4) ? bot4 : top4;
        dst[x * 272 + i * 17 + j] = acc;
    }

    // init scan states — NOTE: Wv has 16*20 = 320 entries and phase A reads up
    // to Wv[315]; round-3 bug was initializing only Wv[0..255]. Cover all 320.
    if (t < 256) {
        VT[t] = (t == 0) ? 1.0f : 0.0f;
    } else {
        Wv[t - 256] = (t == 256) ? 1.0f : 0.0f;   // Wv[0..255]
        if (t < 320) Wv[t] = 0.0f;                // Wv[256..319]
    }
    __syncthreads();

    // ---- 3) split scan: 4 steps, left = waves 0-3 (x=0..3), right = waves 4-7 (x=7..4)
    const int  tr   = t & 255;
    const bool left = (t < 256);
    const int  IA = tr >> 4, jA = tr & 15;     // phase-A roles

    for (int step = 0; step < 4; ++step) {
        if (left) {
            // T[IA,jA][u] = sum_i VT[IA*16+i] * bot[x, i, jA, u]
            const float4* bx = bot4 + step * 272;
            float vv[16];
            *(float4*)&vv[0]  = *(const float4*)(VT + IA * 16 + 0);
            *(float4*)&vv[4]  = *(const float4*)(VT + IA * 16 + 4);
            *(float4*)&vv[8]  = *(const float4*)(VT + IA * 16 + 8);
            *(float4*)&vv[12] = *(const float4*)(VT + IA * 16 + 12);
            float4 acc = make_float4(0.f, 0.f, 0.f, 0.f);
            #pragma unroll
            for (int i = 0; i < 16; ++i) {
                const float4 bv = bx[i * 17 + jA];
                acc.x = fmaf(vv[i], bv.x, acc.x);
                acc.y = fmaf(vv[i], bv.y, acc.y);
                acc.z = fmaf(vv[i], bv.z, acc.z);
                acc.w = fmaf(vv[i], bv.w, acc.w);
            }
            T4[IA * 16 + jA] = acc;
        } else {
            // U[IA,jA][u] = sum_J top[x, IA, J, u] * w[jA,J]
            const float4* tx = top4 + (7 - step) * 272;
            float ww[16];
            *(float4*)&ww[0]  = *(const float4*)(Wv + jA * 20 + 0);
            *(float4*)&ww[4]  = *(const float4*)(Wv + jA * 20 + 4);
            *(float4*)&ww[8]  = *(const float4*)(Wv + jA * 20 + 8);
            *(float4*)&ww[12] = *(const float4*)(Wv + jA * 20 + 12);
            float4 acc = make_float4(0.f, 0.f, 0.f, 0.f);
            #pragma unroll
            for (int J = 0; J < 16; ++J) {
                const float4 tv = tx[IA * 17 + J];
                acc.x = fmaf(ww[J], tv.x, acc.x);
                acc.y = fmaf(ww[J], tv.y, acc.y);
                acc.z = fmaf(ww[J], tv.z, acc.z);
                acc.w = fmaf(ww[J], tv.w, acc.w);
            }
            U4[IA * 17 + jA] = acc;
        }
        __syncthreads();
        if (left) {
            // v'[j,J] = sum_{I,u} T[I,j,u] * top[x,I,J,u];  store VT[J*16+j]
            const int jB = tr >> 4, JB = tr & 15;
            const float4* tx = top4 + step * 272;
            float acc = 0.f;
            #pragma unroll
            for (int I = 0; I < 16; ++I) {
                const float4 tv = T4[I * 16 + jB];
                const float4 pv = tx[I * 17 + JB];
                acc = fmaf(tv.x, pv.x, acc);
                acc = fmaf(tv.y, pv.y, acc);
                acc = fmaf(tv.z, pv.z, acc);
                acc = fmaf(tv.w, pv.w, acc);
            }
            VT[JB * 16 + jB] = acc;
        } else {
            // w'[i,I] = sum_{j,u} bot[x,i,j,u] * U[I,j,u];  store Wv[i*20+I]
            const int iB = tr >> 4, IB = tr & 15;
            const float4* bx = bot4 + (7 - step) * 272;
            float acc = 0.f;
            #pragma unroll
            for (int j = 0; j < 16; ++j) {
                const float4 bv = bx[iB * 17 + j];
                const float4 uv = U4[IB * 17 + j];
                acc = fmaf(bv.x, uv.x, acc);
                acc = fmaf(bv.y, uv.y, acc);
                acc = fmaf(bv.z, uv.z, acc);
                acc = fmaf(bv.w, uv.w, acc);
            }
            Wv[iB * 20 + IB] = acc;
        }
        __syncthreads();
    }

    // ---- out = vL . w : vL[i*16+I] = VT[I*16+i] (t=I*16+i -> i=t&15, I=t>>4)
    if (t < 256) {
        float p = VT[t] * Wv[(t & 15) * 20 + (t >> 4)];
        #pragma unroll
        for (int off = 32; off > 0; off >>= 1) p += __shfl_down(p, off, 64);
        if ((t & 63) == 0) red[t >> 6] = p;
    }
    __syncthreads();
    if (t == 0) out[b] = red[0] + red[1] + red[2] + red[3];
}

// ---------------------------------------------------------------------------
extern "C" void kernel_launch(void* const* d_in, const int* in_sizes, int n_in,
                              void* d_out, int out_size, void* d_ws, size_t ws_size,
                              hipStream_t stream) {
    const int*   cfg = (const int*)  d_in[0];
    const float* A   = (const float*)d_in[1];
    const float* W1  = (const float*)d_in[2];
    const float* b1  = (const float*)d_in[3];
    const float* W2  = (const float*)d_in[4];
    const float* b2  = (const float*)d_in[5];
    float* out   = (float*)d_out;
    float* delta = (float*)d_ws;                  // ncfg * 16384 floats (8 MB)

    const int ncfg = in_sizes[0] / 32;            // 128

    dim3 gA(16, ncfg / 8);                        // (16, 16)
    nn_delta_kernel<<<gA, 256, 0, stream>>>(cfg, W1, b1, W2, b2, delta);
    contract_kernel<<<ncfg, 512, 0, stream>>>(cfg, A, delta, out);
}